// Round 1
// baseline (151.286 us; speedup 1.0000x reference)
//
#include <hip/hip_runtime.h>

#define B_  4
#define C_  64
#define H_  256
#define W_  256
#define h_  64
#define w_  64
// s = 4, off = 2, r = 2, inv_2ss2 = 1/(2*2.5^2) = 0.08
// spatial 1-D weights: exp(-0.32), exp(-0.08), 1
#define SW2 0.72614904f
#define SW1 0.92311635f

// ---------------- per-batch sum / sumsq of guidance (for sigma_range) --------
__global__ void jbu_stats(const float* __restrict__ g, double* __restrict__ stats) {
    // grid = 256 blocks (64 per batch), 256 threads
    int b     = blockIdx.x >> 6;
    int slice = blockIdx.x & 63;
    const int perBatch = 3 * H_ * W_;          // 196608
    const int perBlock = perBatch / 64;        // 3072
    const float* p = g + (size_t)b * perBatch + (size_t)slice * perBlock;
    double s = 0.0, s2 = 0.0;
    for (int i = threadIdx.x; i < perBlock; i += 256) {
        float v = p[i];
        s  += (double)v;
        s2 += (double)v * (double)v;
    }
    for (int off = 32; off > 0; off >>= 1) {
        s  += __shfl_down(s,  off);
        s2 += __shfl_down(s2, off);
    }
    __shared__ double ls[8];
    int wid  = threadIdx.x >> 6;
    int lane = threadIdx.x & 63;
    if (lane == 0) { ls[wid] = s; ls[4 + wid] = s2; }
    __syncthreads();
    if (threadIdx.x == 0) {
        double S  = ls[0] + ls[1] + ls[2] + ls[3];
        double S2 = ls[4] + ls[5] + ls[6] + ls[7];
        atomicAdd(&stats[b],     S);
        atomicAdd(&stats[4 + b], S2);
    }
}

// ---------------- transpose source (B,C,h,w) -> (B,h,w,C) --------------------
__global__ void jbu_transpose(const float* __restrict__ src, float* __restrict__ dst) {
    // grid = B*h = 256 blocks, 256 threads; block handles (b,y): tile c(64) x x(64)
    __shared__ float tile[64 * 65];
    int b = blockIdx.x >> 6;
    int y = blockIdx.x & 63;
    const float* sp = src + (size_t)b * C_ * h_ * w_ + (size_t)y * w_;
    int tx = threadIdx.x & 63;
    int tc = threadIdx.x >> 6;      // 0..3
    #pragma unroll
    for (int i = 0; i < 16; ++i) {
        int c = tc + i * 4;
        tile[c * 65 + tx] = sp[(size_t)c * (h_ * w_) + tx];  // coalesced read
    }
    __syncthreads();
    float* dp = dst + (((size_t)b * h_ + y) * w_) * C_;
    int cc = threadIdx.x & 63;
    int xw = threadIdx.x >> 6;
    #pragma unroll
    for (int i = 0; i < 16; ++i) {
        int x = xw + i * 4;
        dp[(size_t)x * C_ + cc] = tile[cc * 65 + x];         // coalesced write
    }
}

// ---------------- main JBU kernel --------------------------------------------
// block = 256 threads (lane over x = 0..255); blockIdx = ((b*64 + y4)*4 + cg)
// thread: 4 fine pixels (y = y4*4 + 0..3, fixed x) x 16 channels (cg*16 ..)
template <int TRANSPOSED>
__global__ __launch_bounds__(256, 4)
void jbu_main(const float* __restrict__ srcp, const float* __restrict__ guid,
              const double* __restrict__ stats, float* __restrict__ out) {
    int cg = blockIdx.x & 3;
    int y4 = (blockIdx.x >> 2) & 63;
    int b  = blockIdx.x >> 8;
    int x  = threadIdx.x;

    // sigma_range: sigma = 0.5*std(ddof=1) -> inv_2sr2 = 1/(2*0.25*var) = 2/var
    const double n = 3.0 * H_ * W_;
    double S  = stats[b];
    double S2 = stats[4 + b];
    double var = (S2 - S * S / n) / (n - 1.0);
    float invr = (float)(2.0 / var);

    const float sw[5] = {SW2, SW1, 1.0f, SW1, SW2};

    const float* gb = guid + (size_t)b * 3 * H_ * W_;
    int y0 = y4 * 4;

    float gpix[4][3];
    #pragma unroll
    for (int p = 0; p < 4; ++p)
        #pragma unroll
        for (int k = 0; k < 3; ++k)
            gpix[p][k] = gb[(size_t)k * H_ * W_ + (size_t)(y0 + p) * W_ + x];

    int xb = x >> 2;
    int xi[5], yi[5];
    #pragma unroll
    for (int d = 0; d < 5; ++d) {
        int v = xb + d - 2; xi[d] = v < 0 ? 0 : (v > w_ - 1 ? w_ - 1 : v);
        int u = y4 + d - 2; yi[d] = u < 0 ? 0 : (u > h_ - 1 ? h_ - 1 : u);
    }

    float acc[4][16];
    float den[4];
    #pragma unroll
    for (int p = 0; p < 4; ++p) {
        den[p] = 0.0f;
        #pragma unroll
        for (int c = 0; c < 16; ++c) acc[p][c] = 0.0f;
    }

    const float* srcb = TRANSPOSED
        ? srcp + (size_t)b * h_ * w_ * C_            // (y,x,c)
        : srcp + (size_t)b * C_ * h_ * w_;           // (c,y,x)

    for (int dy = 0; dy < 5; ++dy) {
        int   yy  = yi[dy];
        int   gy  = yy * 4 + 2;
        float swy = sw[dy];
        #pragma unroll
        for (int dx = 0; dx < 5; ++dx) {
            int xx = xi[dx];
            int gx = xx * 4 + 2;
            float gl0 = gb[0 * H_ * W_ + gy * W_ + gx];
            float gl1 = gb[1 * H_ * W_ + gy * W_ + gx];
            float gl2 = gb[2 * H_ * W_ + gy * W_ + gx];
            float swxy = swy * sw[dx];
            float wgt[4];
            #pragma unroll
            for (int p = 0; p < 4; ++p) {
                float d0 = gpix[p][0] - gl0;
                float d1 = gpix[p][1] - gl1;
                float d2 = gpix[p][2] - gl2;
                float diff2 = d0 * d0 + d1 * d1 + d2 * d2;
                float wv = swxy * __expf(-diff2 * invr);
                wgt[p] = wv;
                den[p] += wv;
            }
            if (TRANSPOSED) {
                const float* sp = srcb + ((size_t)yy * w_ + xx) * C_ + cg * 16;
                const float4* spv = (const float4*)sp;
                #pragma unroll
                for (int q = 0; q < 4; ++q) {
                    float4 sv = spv[q];
                    #pragma unroll
                    for (int p = 0; p < 4; ++p) {
                        acc[p][q * 4 + 0] += wgt[p] * sv.x;
                        acc[p][q * 4 + 1] += wgt[p] * sv.y;
                        acc[p][q * 4 + 2] += wgt[p] * sv.z;
                        acc[p][q * 4 + 3] += wgt[p] * sv.w;
                    }
                }
            } else {
                const float* sp = srcb + ((size_t)(cg * 16) * h_ + yy) * w_ + xx;
                #pragma unroll
                for (int c = 0; c < 16; ++c) {
                    float sv = sp[(size_t)c * h_ * w_];
                    #pragma unroll
                    for (int p = 0; p < 4; ++p) acc[p][c] += wgt[p] * sv;
                }
            }
        }
    }

    float* ob = out + ((size_t)b * C_ + cg * 16) * H_ * W_;
    #pragma unroll
    for (int p = 0; p < 4; ++p) {
        float r = 1.0f / (den[p] + 1e-8f);
        int row = (y0 + p) * W_ + x;
        #pragma unroll
        for (int c = 0; c < 16; ++c) {
            ob[(size_t)c * H_ * W_ + row] = acc[p][c] * r;
        }
    }
}

extern "C" void kernel_launch(void* const* d_in, const int* in_sizes, int n_in,
                              void* d_out, int out_size, void* d_ws, size_t ws_size,
                              hipStream_t stream) {
    const float* src  = (const float*)d_in[0];   // (4,64,64,64)
    const float* guid = (const float*)d_in[1];   // (4,3,256,256)
    float* out = (float*)d_out;                  // (4,64,256,256)

    double* stats = (double*)d_ws;               // 8 doubles: sum[4], sumsq[4]
    float*  srcT  = (float*)((char*)d_ws + 256); // transposed source (B,h,w,C)
    size_t needT = 256 + (size_t)B_ * h_ * w_ * C_ * sizeof(float);

    hipMemsetAsync(d_ws, 0, 64, stream);
    jbu_stats<<<256, 256, 0, stream>>>(guid, stats);

    if (ws_size >= needT) {
        jbu_transpose<<<256, 256, 0, stream>>>(src, srcT);
        jbu_main<1><<<B_ * 64 * 4, 256, 0, stream>>>(srcT, guid, stats, out);
    } else {
        jbu_main<0><<<B_ * 64 * 4, 256, 0, stream>>>(src, guid, stats, out);
    }
}

// Round 2
// 122.283 us; speedup vs baseline: 1.2372x; 1.2372x over previous
//
#include <hip/hip_runtime.h>

#define B_  4
#define C_  64
#define H_  256
#define W_  256
#define h_  64
#define w_  64
// s = 4, off = 2, r = 2, inv_2ss2 = 1/(2*2.5^2) = 0.08
// spatial 1-D weights: exp(-0.32), exp(-0.08), 1
#define SW2 0.72614904f
#define SW1 0.92311635f

// ---------------- per-batch sum / sumsq of guidance (for sigma_range) --------
__global__ void jbu_stats(const float* __restrict__ g, double* __restrict__ stats) {
    int b     = blockIdx.x >> 6;
    int slice = blockIdx.x & 63;
    const int perBatch = 3 * H_ * W_;          // 196608
    const int perBlock = perBatch / 64;        // 3072
    const float* p = g + (size_t)b * perBatch + (size_t)slice * perBlock;
    double s = 0.0, s2 = 0.0;
    for (int i = threadIdx.x; i < perBlock; i += 256) {
        float v = p[i];
        s  += (double)v;
        s2 += (double)v * (double)v;
    }
    for (int off = 32; off > 0; off >>= 1) {
        s  += __shfl_down(s,  off);
        s2 += __shfl_down(s2, off);
    }
    __shared__ double ls[8];
    int wid  = threadIdx.x >> 6;
    int lane = threadIdx.x & 63;
    if (lane == 0) { ls[wid] = s; ls[4 + wid] = s2; }
    __syncthreads();
    if (threadIdx.x == 0) {
        double S  = ls[0] + ls[1] + ls[2] + ls[3];
        double S2 = ls[4] + ls[5] + ls[6] + ls[7];
        atomicAdd(&stats[b],     S);
        atomicAdd(&stats[4 + b], S2);
    }
}

// stats (doubles) -> per-batch float inv_2sr2 = 2/var
__global__ void jbu_finalize(const double* __restrict__ stats, float* __restrict__ invr) {
    int b = threadIdx.x;
    if (b < B_) {
        const double n = 3.0 * H_ * W_;
        double S  = stats[b];
        double S2 = stats[4 + b];
        double var = (S2 - S * S / n) / (n - 1.0);
        invr[b] = (float)(2.0 / var);
    }
}

// ---------------- transpose source (B,C,h,w) -> (B,h,w,C) --------------------
__global__ void jbu_transpose(const float* __restrict__ src, float* __restrict__ dst) {
    __shared__ float tile[64 * 65];
    int b = blockIdx.x >> 6;
    int y = blockIdx.x & 63;
    const float* sp = src + (size_t)b * C_ * h_ * w_ + (size_t)y * w_;
    int tx = threadIdx.x & 63;
    int tc = threadIdx.x >> 6;      // 0..3
    #pragma unroll
    for (int i = 0; i < 16; ++i) {
        int c = tc + i * 4;
        tile[c * 65 + tx] = sp[(size_t)c * (h_ * w_) + tx];
    }
    __syncthreads();
    float* dp = dst + (((size_t)b * h_ + y) * w_) * C_;
    int cc = threadIdx.x & 63;
    int xw = threadIdx.x >> 6;
    #pragma unroll
    for (int i = 0; i < 16; ++i) {
        int x = xw + i * 4;
        dp[(size_t)x * C_ + cc] = tile[cc * 65 + x];
    }
}

// ---------------- pack guidance: (B,3,H,W) -> float4 (B,H,W,.) and low-res ---
__global__ void jbu_pack(const float* __restrict__ g, float4* __restrict__ gpack,
                         float4* __restrict__ glow) {
    int id = blockIdx.x * 256 + threadIdx.x;
    if (blockIdx.x < 1024) {
        int b = id >> 16, pix = id & 65535;
        const float* gb = g + (size_t)b * 3 * H_ * W_;
        gpack[id] = make_float4(gb[pix], gb[H_ * W_ + pix], gb[2 * H_ * W_ + pix], 0.f);
    } else {
        int i = id - 1024 * 256;          // [0, 16384)
        int b = i >> 12, pix = i & 4095;
        int yy = pix >> 6, xx = pix & 63;
        const float* gb = g + (size_t)b * 3 * H_ * W_;
        int gidx = (yy * 4 + 2) * W_ + (xx * 4 + 2);
        glow[i] = make_float4(gb[gidx], gb[H_ * W_ + gidx], gb[2 * H_ * W_ + gidx], 0.f);
    }
}

// ---------------- main JBU kernel --------------------------------------------
// block = 256 (lane = x); blockIdx = ((b*64 + y4)*8 + cg)
// thread: 4 fine pixels (y = y4*4+p, fixed x) x 8 channels (cg*8..)
__global__ __launch_bounds__(256)
void jbu_main2(const float* __restrict__ srcT, const float4* __restrict__ gpack,
               const float4* __restrict__ glow, const float* __restrict__ invrp,
               float* __restrict__ out) {
    int cg = blockIdx.x & 7;
    int y4 = (blockIdx.x >> 3) & 63;
    int b  = blockIdx.x >> 9;
    int x  = threadIdx.x;

    float invr = invrp[b];
    const float sw[5] = {SW2, SW1, 1.0f, SW1, SW2};
    int y0 = y4 * 4;

    float4 gp[4];
    #pragma unroll
    for (int p = 0; p < 4; ++p)
        gp[p] = gpack[((size_t)b * H_ + (y0 + p)) * W_ + x];

    int xb = x >> 2;
    int xi[5], yi[5];
    #pragma unroll
    for (int d = 0; d < 5; ++d) {
        int v = xb + d - 2; xi[d] = v < 0 ? 0 : (v > w_ - 1 ? w_ - 1 : v);
        int u = y4 + d - 2; yi[d] = u < 0 ? 0 : (u > h_ - 1 ? h_ - 1 : u);
    }

    float acc[4][8];
    float den[4];
    #pragma unroll
    for (int p = 0; p < 4; ++p) {
        den[p] = 0.0f;
        #pragma unroll
        for (int c = 0; c < 8; ++c) acc[p][c] = 0.0f;
    }

    const float*  sb  = srcT + (size_t)b * h_ * w_ * C_ + cg * 8;
    const float4* glb = glow + (size_t)b * h_ * w_;

    for (int dy = 0; dy < 5; ++dy) {
        int   yy  = yi[dy];
        float swy = sw[dy];
        #pragma unroll
        for (int dx = 0; dx < 5; ++dx) {
            int xx = xi[dx];
            float4 gl = glb[yy * w_ + xx];
            float swxy = swy * sw[dx];
            float wgt[4];
            #pragma unroll
            for (int p = 0; p < 4; ++p) {
                float d0 = gp[p].x - gl.x;
                float d1 = gp[p].y - gl.y;
                float d2 = gp[p].z - gl.z;
                float wv = swxy * __expf(-(d0 * d0 + d1 * d1 + d2 * d2) * invr);
                wgt[p] = wv;
                den[p] += wv;
            }
            const float4* sp = (const float4*)(sb + ((size_t)yy * w_ + xx) * C_);
            float4 s0 = sp[0];
            float4 s1 = sp[1];
            #pragma unroll
            for (int p = 0; p < 4; ++p) {
                acc[p][0] += wgt[p] * s0.x;
                acc[p][1] += wgt[p] * s0.y;
                acc[p][2] += wgt[p] * s0.z;
                acc[p][3] += wgt[p] * s0.w;
                acc[p][4] += wgt[p] * s1.x;
                acc[p][5] += wgt[p] * s1.y;
                acc[p][6] += wgt[p] * s1.z;
                acc[p][7] += wgt[p] * s1.w;
            }
        }
    }

    float* ob = out + ((size_t)b * C_ + cg * 8) * H_ * W_;
    #pragma unroll
    for (int p = 0; p < 4; ++p) {
        float r = 1.0f / (den[p] + 1e-8f);
        int row = (y0 + p) * W_ + x;
        #pragma unroll
        for (int c = 0; c < 8; ++c) {
            ob[(size_t)c * H_ * W_ + row] = acc[p][c] * r;
        }
    }
}

// ---------------- fallback (tiny workspace): round-1 style, untransposed -----
__global__ void jbu_main_fb(const float* __restrict__ srcp, const float* __restrict__ guid,
                            const double* __restrict__ stats, float* __restrict__ out) {
    int cg = blockIdx.x & 7;
    int y4 = (blockIdx.x >> 3) & 63;
    int b  = blockIdx.x >> 9;
    int x  = threadIdx.x;

    const double n = 3.0 * H_ * W_;
    double S  = stats[b];
    double S2 = stats[4 + b];
    double var = (S2 - S * S / n) / (n - 1.0);
    float invr = (float)(2.0 / var);

    const float sw[5] = {SW2, SW1, 1.0f, SW1, SW2};
    const float* gb = guid + (size_t)b * 3 * H_ * W_;
    int y0 = y4 * 4;

    float gpix[4][3];
    #pragma unroll
    for (int p = 0; p < 4; ++p)
        #pragma unroll
        for (int k = 0; k < 3; ++k)
            gpix[p][k] = gb[(size_t)k * H_ * W_ + (size_t)(y0 + p) * W_ + x];

    int xb = x >> 2;
    int xi[5], yi[5];
    #pragma unroll
    for (int d = 0; d < 5; ++d) {
        int v = xb + d - 2; xi[d] = v < 0 ? 0 : (v > w_ - 1 ? w_ - 1 : v);
        int u = y4 + d - 2; yi[d] = u < 0 ? 0 : (u > h_ - 1 ? h_ - 1 : u);
    }

    float acc[4][8];
    float den[4];
    #pragma unroll
    for (int p = 0; p < 4; ++p) {
        den[p] = 0.0f;
        #pragma unroll
        for (int c = 0; c < 8; ++c) acc[p][c] = 0.0f;
    }

    const float* srcb = srcp + (size_t)b * C_ * h_ * w_;

    for (int dy = 0; dy < 5; ++dy) {
        int   yy  = yi[dy];
        int   gy  = yy * 4 + 2;
        float swy = sw[dy];
        #pragma unroll
        for (int dx = 0; dx < 5; ++dx) {
            int xx = xi[dx];
            int gx = xx * 4 + 2;
            float gl0 = gb[0 * H_ * W_ + gy * W_ + gx];
            float gl1 = gb[1 * H_ * W_ + gy * W_ + gx];
            float gl2 = gb[2 * H_ * W_ + gy * W_ + gx];
            float swxy = swy * sw[dx];
            float wgt[4];
            #pragma unroll
            for (int p = 0; p < 4; ++p) {
                float d0 = gpix[p][0] - gl0;
                float d1 = gpix[p][1] - gl1;
                float d2 = gpix[p][2] - gl2;
                float wv = swxy * __expf(-(d0 * d0 + d1 * d1 + d2 * d2) * invr);
                wgt[p] = wv;
                den[p] += wv;
            }
            const float* sp = srcb + ((size_t)(cg * 8) * h_ + yy) * w_ + xx;
            #pragma unroll
            for (int c = 0; c < 8; ++c) {
                float sv = sp[(size_t)c * h_ * w_];
                #pragma unroll
                for (int p = 0; p < 4; ++p) acc[p][c] += wgt[p] * sv;
            }
        }
    }

    float* ob = out + ((size_t)b * C_ + cg * 8) * H_ * W_;
    #pragma unroll
    for (int p = 0; p < 4; ++p) {
        float r = 1.0f / (den[p] + 1e-8f);
        int row = (y0 + p) * W_ + x;
        #pragma unroll
        for (int c = 0; c < 8; ++c) {
            ob[(size_t)c * H_ * W_ + row] = acc[p][c] * r;
        }
    }
}

extern "C" void kernel_launch(void* const* d_in, const int* in_sizes, int n_in,
                              void* d_out, int out_size, void* d_ws, size_t ws_size,
                              hipStream_t stream) {
    const float* src  = (const float*)d_in[0];   // (4,64,64,64)
    const float* guid = (const float*)d_in[1];   // (4,3,256,256)
    float* out = (float*)d_out;                  // (4,64,256,256)

    // workspace layout
    double* stats = (double*)d_ws;                         // 8 doubles
    float*  invr  = (float*)((char*)d_ws + 64);            // 4 floats
    char*   base  = (char*)d_ws + 256;
    float*  srcT  = (float*)base;                                        // 4 MiB
    float4* gpack = (float4*)(base + (size_t)4 * 1024 * 1024);           // 4 MiB
    float4* glow  = (float4*)(base + (size_t)8 * 1024 * 1024);           // 256 KiB
    size_t need = 256 + (size_t)8 * 1024 * 1024 + 256 * 1024 + 1024;

    hipMemsetAsync(d_ws, 0, 64, stream);
    jbu_stats<<<256, 256, 0, stream>>>(guid, stats);

    if (ws_size >= need) {
        jbu_finalize<<<1, 64, 0, stream>>>(stats, invr);
        jbu_transpose<<<256, 256, 0, stream>>>(src, srcT);
        jbu_pack<<<1088, 256, 0, stream>>>(guid, gpack, glow);
        jbu_main2<<<B_ * 64 * 8, 256, 0, stream>>>(srcT, gpack, glow, invr, out);
    } else {
        jbu_main_fb<<<B_ * 64 * 8, 256, 0, stream>>>(src, guid, stats, out);
    }
}

// Round 3
// 111.282 us; speedup vs baseline: 1.3595x; 1.0989x over previous
//
#include <hip/hip_runtime.h>

#define B_  4
#define C_  64
#define H_  256
#define W_  256
#define h_  64
#define w_  64
// s = 4, off = 2, r = 2, inv_2ss2 = 1/(2*2.5^2) = 0.08
// log2-domain spatial weights: -(d^2)*0.08*log2(e)
#define L2SW2 (-0.46166241f)
#define L2SW1 (-0.11541560f)

// ---------------- per-batch sum / sumsq of guidance (for sigma_range) --------
__global__ void jbu_stats(const float* __restrict__ g, double* __restrict__ stats) {
    int b     = blockIdx.x >> 6;
    int slice = blockIdx.x & 63;
    const int perBatch = 3 * H_ * W_;          // 196608
    const int perBlock = perBatch / 64;        // 3072
    const float* p = g + (size_t)b * perBatch + (size_t)slice * perBlock;
    double s = 0.0, s2 = 0.0;
    for (int i = threadIdx.x; i < perBlock; i += 256) {
        float v = p[i];
        s  += (double)v;
        s2 += (double)v * (double)v;
    }
    for (int off = 32; off > 0; off >>= 1) {
        s  += __shfl_down(s,  off);
        s2 += __shfl_down(s2, off);
    }
    __shared__ double ls[8];
    int wid  = threadIdx.x >> 6;
    int lane = threadIdx.x & 63;
    if (lane == 0) { ls[wid] = s; ls[4 + wid] = s2; }
    __syncthreads();
    if (threadIdx.x == 0) {
        double S  = ls[0] + ls[1] + ls[2] + ls[3];
        double S2 = ls[4] + ls[5] + ls[6] + ls[7];
        atomicAdd(&stats[b],     S);
        atomicAdd(&stats[4 + b], S2);
    }
}

// ---------------- fused main kernel ------------------------------------------
// grid = ((b*64 + y4)*8 + cg), block = 256 (lane = fine x)
// thread: 4 fine y (y4*4+p) x fixed x x 8 channels (cg*8..)
// Per-block LDS staging of the 5x64 coarse source tile (8 ch) and low-res
// guidance (3 ch), loaded coalesced from the ORIGINAL layouts.
__global__ __launch_bounds__(256)
void jbu_mega(const float* __restrict__ src, const float* __restrict__ guid,
              const double* __restrict__ stats, float* __restrict__ out) {
    // src stride 12 floats (48B: b128-aligned, 16 addrs -> 8 banks -> 2-way = free)
    __shared__ __align__(16) float sS[5 * 64 * 12];   // 15360 B
    // glow stride 4 floats (16B aligned, 2-way = free)
    __shared__ __align__(16) float sG[5 * 64 * 4];    //  5120 B

    int cg = blockIdx.x & 7;
    int y4 = (blockIdx.x >> 3) & 63;
    int b  = blockIdx.x >> 9;
    int tid = threadIdx.x;

    int yi[5];
    #pragma unroll
    for (int d = 0; d < 5; ++d) {
        int u = y4 + d - 2;
        yi[d] = u < 0 ? 0 : (u > h_ - 1 ? h_ - 1 : u);
    }

    // ---- stage source tile: 5 rows x 8 ch x 64 x (coalesced 256B runs) ----
    #pragma unroll
    for (int it = 0; it < 10; ++it) {
        int k   = tid + it * 256;          // < 2560
        int xx  = k & 63;
        int cr  = k >> 6;                  // 0..39
        int row = cr >> 3;                 // 0..4
        int cc  = cr & 7;                  // 0..7
        sS[(row * 64 + xx) * 12 + cc] =
            src[(((size_t)b * C_ + cg * 8 + cc) * h_ + yi[row]) * w_ + xx];
    }
    // ---- stage low-res guidance: 5 rows x 3 ch x 64 x ----
    {
        int k = tid;                       // two iters cover 960
        #pragma unroll
        for (int it = 0; it < 4; ++it) {
            if (k < 960) {
                int xx  = k & 63;
                int cr  = k >> 6;          // 0..14
                int row = cr / 3;
                int c   = cr - row * 3;
                sG[(row * 64 + xx) * 4 + c] =
                    guid[(((size_t)b * 3 + c) * H_ + (yi[row] * 4 + 2)) * W_ + (xx * 4 + 2)];
            }
            k += 256;
        }
    }

    // ---- inv_2sr2 in log2 domain (once per block; cheap doubles) ----
    const double n = 3.0 * H_ * W_;
    double S  = stats[b];
    double S2 = stats[4 + b];
    double var = (S2 - S * S / n) / (n - 1.0);
    float invrl2 = (float)(2.0 / var) * 1.44269504f;

    __syncthreads();

    int x  = tid;
    int y0 = y4 * 4;

    // high-res guidance pixels (coalesced scalar loads from original layout)
    float gp[4][3];
    #pragma unroll
    for (int c = 0; c < 3; ++c)
        #pragma unroll
        for (int p = 0; p < 4; ++p)
            gp[p][c] = guid[(((size_t)b * 3 + c) * H_ + (y0 + p)) * W_ + x];

    int xb = x >> 2;
    int xi[5];
    #pragma unroll
    for (int d = 0; d < 5; ++d) {
        int v = xb + d - 2;
        xi[d] = v < 0 ? 0 : (v > w_ - 1 ? w_ - 1 : v);
    }

    const float l2sw[5] = {L2SW2, L2SW1, 0.0f, L2SW1, L2SW2};

    float acc[4][8];
    float den[4];
    #pragma unroll
    for (int p = 0; p < 4; ++p) {
        den[p] = 0.0f;
        #pragma unroll
        for (int c = 0; c < 8; ++c) acc[p][c] = 0.0f;
    }

    #pragma unroll
    for (int dy = 0; dy < 5; ++dy) {
        float l2y = l2sw[dy];
        int   rb  = dy * 64;
        #pragma unroll
        for (int dx = 0; dx < 5; ++dx) {
            int xx = xi[dx];
            float4 gl = *(const float4*)&sG[(rb + xx) * 4];
            float l2xy = l2y + l2sw[dx];
            float wgt[4];
            #pragma unroll
            for (int p = 0; p < 4; ++p) {
                float d0 = gp[p][0] - gl.x;
                float d1 = gp[p][1] - gl.y;
                float d2 = gp[p][2] - gl.z;
                float diff2 = fmaf(d2, d2, fmaf(d1, d1, d0 * d0));
                float wv = __builtin_amdgcn_exp2f(fmaf(diff2, -invrl2, l2xy));
                wgt[p] = wv;
                den[p] += wv;
            }
            const float* sP = &sS[(rb + xx) * 12];
            float4 s0 = *(const float4*)sP;
            float4 s1 = *(const float4*)(sP + 4);
            #pragma unroll
            for (int p = 0; p < 4; ++p) {
                acc[p][0] = fmaf(wgt[p], s0.x, acc[p][0]);
                acc[p][1] = fmaf(wgt[p], s0.y, acc[p][1]);
                acc[p][2] = fmaf(wgt[p], s0.z, acc[p][2]);
                acc[p][3] = fmaf(wgt[p], s0.w, acc[p][3]);
                acc[p][4] = fmaf(wgt[p], s1.x, acc[p][4]);
                acc[p][5] = fmaf(wgt[p], s1.y, acc[p][5]);
                acc[p][6] = fmaf(wgt[p], s1.z, acc[p][6]);
                acc[p][7] = fmaf(wgt[p], s1.w, acc[p][7]);
            }
        }
    }

    float* ob = out + ((size_t)b * C_ + cg * 8) * H_ * W_;
    #pragma unroll
    for (int p = 0; p < 4; ++p) {
        float r = 1.0f / (den[p] + 1e-8f);
        int row = (y0 + p) * W_ + x;
        #pragma unroll
        for (int c = 0; c < 8; ++c) {
            ob[(size_t)c * H_ * W_ + row] = acc[p][c] * r;
        }
    }
}

extern "C" void kernel_launch(void* const* d_in, const int* in_sizes, int n_in,
                              void* d_out, int out_size, void* d_ws, size_t ws_size,
                              hipStream_t stream) {
    const float* src  = (const float*)d_in[0];   // (4,64,64,64)
    const float* guid = (const float*)d_in[1];   // (4,3,256,256)
    float* out = (float*)d_out;                  // (4,64,256,256)

    double* stats = (double*)d_ws;               // 8 doubles: sum[4], sumsq[4]

    hipMemsetAsync(d_ws, 0, 64, stream);
    jbu_stats<<<256, 256, 0, stream>>>(guid, stats);
    jbu_mega<<<B_ * 64 * 8, 256, 0, stream>>>(src, guid, stats, out);
}

// Round 4
// 97.727 us; speedup vs baseline: 1.5480x; 1.1387x over previous
//
#include <hip/hip_runtime.h>

#define B_  4
#define C_  64
#define H_  256
#define W_  256
#define h_  64
#define w_  64
// s = 4, off = 2, r = 2, inv_2ss2 = 1/(2*2.5^2) = 0.08
// log2-domain spatial weights: -(d^2)*0.08*log2(e)
#define L2SW2 (-0.46166241f)
#define L2SW1 (-0.11541560f)

// ---------------- per-batch partial sum / sumsq of guidance ------------------
// grid = 128 blocks (32 per batch); writes partials, NO atomics, no init needed.
__global__ void jbu_stats(const float* __restrict__ g, double* __restrict__ stats) {
    int b     = blockIdx.x >> 5;
    int slice = blockIdx.x & 31;
    // per batch: 3*256*256 = 196608 floats = 49152 float4; per block: 1536 float4
    const float4* p = (const float4*)(g + (size_t)b * 3 * H_ * W_) + (size_t)slice * 1536;
    double s = 0.0, s2 = 0.0;
    for (int i = threadIdx.x; i < 1536; i += 256) {
        float4 v = p[i];
        s  += (double)v.x + (double)v.y + (double)v.z + (double)v.w;
        s2 += (double)v.x * v.x + (double)v.y * v.y
            + (double)v.z * v.z + (double)v.w * v.w;
    }
    for (int off = 32; off > 0; off >>= 1) {
        s  += __shfl_down(s,  off);
        s2 += __shfl_down(s2, off);
    }
    __shared__ double ls[8];
    int wid  = threadIdx.x >> 6;
    int lane = threadIdx.x & 63;
    if (lane == 0) { ls[wid] = s; ls[4 + wid] = s2; }
    __syncthreads();
    if (threadIdx.x == 0) {
        stats[blockIdx.x]       = ls[0] + ls[1] + ls[2] + ls[3];
        stats[128 + blockIdx.x] = ls[4] + ls[5] + ls[6] + ls[7];
    }
}

// ---------------- fused main kernel ------------------------------------------
// grid = ((b*64 + y4)*4 + cg), 1024 blocks; block = 256 (lane = fine x)
// thread: 4 fine y (y4*4+p) x fixed x x 16 channels (cg*16..)
__global__ __launch_bounds__(256, 4)
void jbu_mega16(const float* __restrict__ src, const float* __restrict__ guid,
                const double* __restrict__ stats, float* __restrict__ out) {
    // src tile: 5 rows x 64 cols x 16 ch, stride padded to 20 floats (80 B):
    // xx*20 mod 32 has period 8 -> 2 addrs/bank-group on reads = conflict-free,
    // and 80 B keeps every 16-B sub-quad b128-aligned.
    __shared__ __align__(16) float sS[5 * 64 * 20];   // 25600 B
    __shared__ __align__(16) float sG[5 * 64 * 4];    //  5120 B

    int cg  = blockIdx.x & 3;
    int y4  = (blockIdx.x >> 2) & 63;
    int b   = blockIdx.x >> 8;
    int tid = threadIdx.x;

    // ---- stage source tile: 5 rows x 16 ch x 64 x, coalesced 256-B runs ----
    const float* sb = src + ((size_t)b * C_ + cg * 16) * h_ * w_;
    #pragma unroll
    for (int it = 0; it < 20; ++it) {
        int k   = tid + it * 256;          // < 5120
        int xx  = k & 63;
        int cr  = k >> 6;                  // 0..79
        int row = cr >> 4;                 // 0..4
        int cc  = cr & 15;                 // 0..15
        int u   = y4 + row - 2;
        int yy  = u < 0 ? 0 : (u > h_ - 1 ? h_ - 1 : u);
        sS[(row * 64 + xx) * 20 + cc] = sb[((size_t)cc * h_ + yy) * w_ + xx];
    }
    // ---- stage low-res guidance: 5 rows x 3 ch x 64 x ----
    {
        int k = tid;
        #pragma unroll
        for (int it = 0; it < 4; ++it) {
            if (k < 960) {
                int xx  = k & 63;
                int cr  = k >> 6;          // 0..14
                int row = cr / 3;
                int c   = cr - row * 3;
                int u   = y4 + row - 2;
                int yy  = u < 0 ? 0 : (u > h_ - 1 ? h_ - 1 : u);
                sG[(row * 64 + xx) * 4 + c] =
                    guid[(((size_t)b * 3 + c) * H_ + (yy * 4 + 2)) * W_ + (xx * 4 + 2)];
            }
            k += 256;
        }
    }

    // ---- inv_2sr2 from partials (uniform scalar loads, once per block) ----
    double S = 0.0, S2 = 0.0;
    for (int i = 0; i < 32; ++i) {
        S  += stats[b * 32 + i];
        S2 += stats[128 + b * 32 + i];
    }
    const double n = 3.0 * H_ * W_;
    double var = (S2 - S * S / n) / (n - 1.0);
    float invrl2 = (float)(2.0 / var) * 1.44269504f;

    __syncthreads();

    int x  = tid;
    int y0 = y4 * 4;

    // high-res guidance pixels (coalesced)
    float gp[4][3];
    #pragma unroll
    for (int c = 0; c < 3; ++c)
        #pragma unroll
        for (int p = 0; p < 4; ++p)
            gp[p][c] = guid[(((size_t)b * 3 + c) * H_ + (y0 + p)) * W_ + x];

    int xb = x >> 2;
    int xi[5];
    #pragma unroll
    for (int d = 0; d < 5; ++d) {
        int v = xb + d - 2;
        xi[d] = v < 0 ? 0 : (v > w_ - 1 ? w_ - 1 : v);
    }

    const float l2sw[5] = {L2SW2, L2SW1, 0.0f, L2SW1, L2SW2};

    float acc[4][16];
    float den[4];
    #pragma unroll
    for (int p = 0; p < 4; ++p) {
        den[p] = 0.0f;
        #pragma unroll
        for (int c = 0; c < 16; ++c) acc[p][c] = 0.0f;
    }

    #pragma unroll
    for (int dy = 0; dy < 5; ++dy) {
        float l2y = l2sw[dy];
        int   rb  = dy * 64;
        #pragma unroll
        for (int dx = 0; dx < 5; ++dx) {
            int xx = xi[dx];
            float4 gl = *(const float4*)&sG[(rb + xx) * 4];
            float l2xy = l2y + l2sw[dx];
            float wgt[4];
            #pragma unroll
            for (int p = 0; p < 4; ++p) {
                float d0 = gp[p][0] - gl.x;
                float d1 = gp[p][1] - gl.y;
                float d2 = gp[p][2] - gl.z;
                float diff2 = fmaf(d2, d2, fmaf(d1, d1, d0 * d0));
                float wv = __builtin_amdgcn_exp2f(fmaf(diff2, -invrl2, l2xy));
                wgt[p] = wv;
                den[p] += wv;
            }
            const float* sP = &sS[(rb + xx) * 20];
            #pragma unroll
            for (int q = 0; q < 4; ++q) {
                float4 sv = *(const float4*)(sP + q * 4);
                #pragma unroll
                for (int p = 0; p < 4; ++p) {
                    acc[p][q * 4 + 0] = fmaf(wgt[p], sv.x, acc[p][q * 4 + 0]);
                    acc[p][q * 4 + 1] = fmaf(wgt[p], sv.y, acc[p][q * 4 + 1]);
                    acc[p][q * 4 + 2] = fmaf(wgt[p], sv.z, acc[p][q * 4 + 2]);
                    acc[p][q * 4 + 3] = fmaf(wgt[p], sv.w, acc[p][q * 4 + 3]);
                }
            }
        }
    }

    float* ob = out + ((size_t)b * C_ + cg * 16) * H_ * W_;
    #pragma unroll
    for (int p = 0; p < 4; ++p) {
        float r = 1.0f / (den[p] + 1e-8f);
        int row = (y0 + p) * W_ + x;
        #pragma unroll
        for (int c = 0; c < 16; ++c) {
            ob[(size_t)c * H_ * W_ + row] = acc[p][c] * r;
        }
    }
}

extern "C" void kernel_launch(void* const* d_in, const int* in_sizes, int n_in,
                              void* d_out, int out_size, void* d_ws, size_t ws_size,
                              hipStream_t stream) {
    const float* src  = (const float*)d_in[0];   // (4,64,64,64)
    const float* guid = (const float*)d_in[1];   // (4,3,256,256)
    float* out = (float*)d_out;                  // (4,64,256,256)

    double* stats = (double*)d_ws;               // 256 doubles: sum[128], sumsq[128]

    jbu_stats<<<128, 256, 0, stream>>>(guid, stats);
    jbu_mega16<<<B_ * 64 * 4, 256, 0, stream>>>(src, guid, stats, out);
}

// Round 5
// 96.586 us; speedup vs baseline: 1.5663x; 1.0118x over previous
//
#include <hip/hip_runtime.h>

#define B_  4
#define C_  64
#define H_  256
#define W_  256
#define h_  64
#define w_  64
// s = 4, off = 2, r = 2, inv_2ss2 = 1/(2*2.5^2) = 0.08
// log2-domain spatial weights: -(d^2)*0.08*log2(e)
#define L2SW2 (-0.46166241f)
#define L2SW1 (-0.11541560f)

// ---------------- per-batch partial sum / sumsq of guidance ------------------
// grid = 128 blocks (32 per batch); writes partials, NO atomics, no init needed.
__global__ void jbu_stats(const float* __restrict__ g, double* __restrict__ stats) {
    int b     = blockIdx.x >> 5;
    int slice = blockIdx.x & 31;
    // per batch: 3*256*256 = 196608 floats = 49152 float4; per block: 1536 float4
    const float4* p = (const float4*)(g + (size_t)b * 3 * H_ * W_) + (size_t)slice * 1536;
    double s = 0.0, s2 = 0.0;
    for (int i = threadIdx.x; i < 1536; i += 256) {
        float4 v = p[i];
        s  += (double)v.x + (double)v.y + (double)v.z + (double)v.w;
        s2 += (double)v.x * v.x + (double)v.y * v.y
            + (double)v.z * v.z + (double)v.w * v.w;
    }
    for (int off = 32; off > 0; off >>= 1) {
        s  += __shfl_down(s,  off);
        s2 += __shfl_down(s2, off);
    }
    __shared__ double ls[8];
    int wid  = threadIdx.x >> 6;
    int lane = threadIdx.x & 63;
    if (lane == 0) { ls[wid] = s; ls[4 + wid] = s2; }
    __syncthreads();
    if (threadIdx.x == 0) {
        stats[blockIdx.x]       = ls[0] + ls[1] + ls[2] + ls[3];
        stats[128 + blockIdx.x] = ls[4] + ls[5] + ls[6] + ls[7];
    }
}

// ---------------- fused main kernel ------------------------------------------
// grid = ((b*64 + y4)*4 + cg), 1024 blocks; block = 256 (lane = fine x)
// thread: 4 fine y (y4*4+p) x fixed x x 16 channels (cg*16..)
__global__ __launch_bounds__(256, 4)
void jbu_mega16(const float* __restrict__ src, const float* __restrict__ guid,
                const double* __restrict__ stats, float* __restrict__ out) {
    // src tile: 5 rows x 64 cols x 16 ch, stride padded to 20 floats (80 B):
    // read side: 4 lanes broadcast same addr, 16 xb values -> ~2 addrs/bank = free.
    __shared__ __align__(16) float sS[5 * 64 * 20];   // 25600 B
    // glow: (r,g,b, B-term) per coarse pixel, B = -invrl2*|gl|^2
    __shared__ __align__(16) float sG[5 * 64 * 4];    //  5120 B

    int cg  = blockIdx.x & 3;
    int y4  = (blockIdx.x >> 2) & 63;
    int b   = blockIdx.x >> 8;
    int tid = threadIdx.x;

    // ---- inv_2sr2 (log2 domain) from partials; uniform scalar loads that
    //      overlap the source staging below (no data dependency).
    double S = 0.0, S2 = 0.0;
    for (int i = 0; i < 32; ++i) {
        S  += stats[b * 32 + i];
        S2 += stats[128 + b * 32 + i];
    }
    const double n = 3.0 * H_ * W_;
    double var = (S2 - S * S / n) / (n - 1.0);
    float invrl2 = (float)(2.0 / var) * 1.44269504f;   // includes log2(e)

    int yi[5];
    #pragma unroll
    for (int d = 0; d < 5; ++d) {
        int u = y4 + d - 2;
        yi[d] = u < 0 ? 0 : (u > h_ - 1 ? h_ - 1 : u);
    }

    // ---- stage source tile: per iter 4 coalesced dword loads + 1 b128 write
    //      (entries: 5 rows x 64 xx x 4 ch-quads; threads = 64 xx x 4 quads)
    const float* sb = src + ((size_t)b * C_ + cg * 16) * h_ * w_;
    {
        int xx0 = tid & 63;
        int j4  = ((tid >> 6) & 3) * 4;    // channel-quad base
        #pragma unroll
        for (int it = 0; it < 5; ++it) {
            int yy = yi[it];               // static index (unrolled)
            float4 v;
            v.x = sb[((size_t)(j4 + 0) * h_ + yy) * w_ + xx0];
            v.y = sb[((size_t)(j4 + 1) * h_ + yy) * w_ + xx0];
            v.z = sb[((size_t)(j4 + 2) * h_ + yy) * w_ + xx0];
            v.w = sb[((size_t)(j4 + 3) * h_ + yy) * w_ + xx0];
            *(float4*)&sS[(it * 64 + xx0) * 20 + j4] = v;
        }
    }
    // ---- stage low-res guidance + B-term: 320 entries, 2 strided iters ----
    for (int k = tid; k < 320; k += 256) {
        int xx  = k & 63;
        int row = k >> 6;
        int u   = y4 + row - 2;
        int yy  = u < 0 ? 0 : (u > h_ - 1 ? h_ - 1 : u);
        const float* gbase = guid + (size_t)b * 3 * H_ * W_
                           + (size_t)(yy * 4 + 2) * W_ + (xx * 4 + 2);
        float gx = gbase[0];
        float gy = gbase[H_ * W_];
        float gz = gbase[2 * H_ * W_];
        float ss = fmaf(gz, gz, fmaf(gy, gy, gx * gx));
        float4 e = make_float4(gx, gy, gz, -invrl2 * ss);
        *(float4*)&sG[(row * 64 + xx) * 4] = e;
    }

    __syncthreads();

    int x  = tid;
    int y0 = y4 * 4;

    // high-res guidance: premultiply by 2*invrl2; A_p = -invrl2*|gp|^2
    float gp[4][3];
    float A[4];
    #pragma unroll
    for (int c = 0; c < 3; ++c)
        #pragma unroll
        for (int p = 0; p < 4; ++p)
            gp[p][c] = guid[(((size_t)b * 3 + c) * H_ + (y0 + p)) * W_ + x];
    float t2 = 2.0f * invrl2;
    #pragma unroll
    for (int p = 0; p < 4; ++p) {
        float ss = fmaf(gp[p][2], gp[p][2], fmaf(gp[p][1], gp[p][1], gp[p][0] * gp[p][0]));
        A[p] = -invrl2 * ss;
        gp[p][0] *= t2; gp[p][1] *= t2; gp[p][2] *= t2;
    }

    int xb = x >> 2;
    int xi[5];
    #pragma unroll
    for (int d = 0; d < 5; ++d) {
        int v = xb + d - 2;
        xi[d] = v < 0 ? 0 : (v > w_ - 1 ? w_ - 1 : v);
    }

    const float l2sw[5] = {L2SW2, L2SW1, 0.0f, L2SW1, L2SW2};

    float acc[4][16];
    float den[4];
    #pragma unroll
    for (int p = 0; p < 4; ++p) {
        den[p] = 0.0f;
        #pragma unroll
        for (int c = 0; c < 16; ++c) acc[p][c] = 0.0f;
    }

    #pragma unroll
    for (int dy = 0; dy < 5; ++dy) {
        float l2y = l2sw[dy];
        int   rb  = dy * 64;
        #pragma unroll
        for (int dx = 0; dx < 5; ++dx) {
            int xx = xi[dx];
            float4 gl = *(const float4*)&sG[(rb + xx) * 4];
            float ct = gl.w + (l2y + l2sw[dx]);   // (l2y+l2sw[dx]) folds to const
            float wgt[4];
            #pragma unroll
            for (int p = 0; p < 4; ++p) {
                float m = fmaf(gp[p][2], gl.z,
                          fmaf(gp[p][1], gl.y, gp[p][0] * gl.x));
                float wv = __builtin_amdgcn_exp2f(m + ct + A[p]);
                wgt[p] = wv;
                den[p] += wv;
            }
            const float* sP = &sS[(rb + xx) * 20];
            #pragma unroll
            for (int q = 0; q < 4; ++q) {
                float4 sv = *(const float4*)(sP + q * 4);
                #pragma unroll
                for (int p = 0; p < 4; ++p) {
                    acc[p][q * 4 + 0] = fmaf(wgt[p], sv.x, acc[p][q * 4 + 0]);
                    acc[p][q * 4 + 1] = fmaf(wgt[p], sv.y, acc[p][q * 4 + 1]);
                    acc[p][q * 4 + 2] = fmaf(wgt[p], sv.z, acc[p][q * 4 + 2]);
                    acc[p][q * 4 + 3] = fmaf(wgt[p], sv.w, acc[p][q * 4 + 3]);
                }
            }
        }
    }

    float* ob = out + ((size_t)b * C_ + cg * 16) * H_ * W_;
    #pragma unroll
    for (int p = 0; p < 4; ++p) {
        float r = 1.0f / (den[p] + 1e-8f);
        int row = (y0 + p) * W_ + x;
        #pragma unroll
        for (int c = 0; c < 16; ++c) {
            ob[(size_t)c * H_ * W_ + row] = acc[p][c] * r;
        }
    }
}

extern "C" void kernel_launch(void* const* d_in, const int* in_sizes, int n_in,
                              void* d_out, int out_size, void* d_ws, size_t ws_size,
                              hipStream_t stream) {
    const float* src  = (const float*)d_in[0];   // (4,64,64,64)
    const float* guid = (const float*)d_in[1];   // (4,3,256,256)
    float* out = (float*)d_out;                  // (4,64,256,256)

    double* stats = (double*)d_ws;               // 256 doubles: sum[128], sumsq[128]

    jbu_stats<<<128, 256, 0, stream>>>(guid, stats);
    jbu_mega16<<<B_ * 64 * 4, 256, 0, stream>>>(src, guid, stats, out);
}